// Round 5
// baseline (498.070 us; speedup 1.0000x reference)
//
#include <hip/hip_runtime.h>
#include <hip/hip_bf16.h>
#include <math.h>

#define NB 4
#define NN 4096
#define UU 512

using short8   = __attribute__((ext_vector_type(8))) short;
using bf16x8   = __attribute__((ext_vector_type(8))) __bf16;
using floatx4  = __attribute__((ext_vector_type(4))) float;
using floatx16 = __attribute__((ext_vector_type(16))) float;

__device__ __forceinline__ floatx4 mfma16(short8 a, short8 b, floatx4 c) {
    return __builtin_amdgcn_mfma_f32_16x16x32_bf16(
        __builtin_bit_cast(bf16x8, a), __builtin_bit_cast(bf16x8, b), c, 0, 0, 0);
}
__device__ __forceinline__ floatx16 mfma32(short8 a, short8 b, floatx16 c) {
    return __builtin_amdgcn_mfma_f32_32x32x16_bf16(
        __builtin_bit_cast(bf16x8, a), __builtin_bit_cast(bf16x8, b), c, 0, 0, 0);
}

__device__ __forceinline__ unsigned short f2bf(float f) {
    union { float f; unsigned u; } v; v.f = f;
    return (unsigned short)((v.u + 0x7fffu + ((v.u >> 16) & 1u)) >> 16);
}
__device__ __forceinline__ float bf2f(unsigned short s) {
    union { unsigned u; float f; } v; v.u = ((unsigned)s) << 16; return v.f;
}

#define GLL16(gp, lp) __builtin_amdgcn_global_load_lds( \
    (const __attribute__((address_space(1))) void*)(gp), \
    (__attribute__((address_space(3))) void*)(lp), 16, 0, 0)

// lgkm-only barrier: does NOT drain outstanding global_load_lds (vmcnt),
// so staging issued earlier stays in flight across it.
#define BAR_LGKM asm volatile("s_waitcnt lgkmcnt(0)\n\ts_barrier" ::: "memory")
// full barrier: drains staging DMA too (iteration boundary)
#define BAR_ALL  asm volatile("s_waitcnt vmcnt(0) lgkmcnt(0)\n\ts_barrier" ::: "memory")

// ---------------------------------------------------------------- converts
__global__ void __launch_bounds__(256) k_cvt_x(const float* __restrict__ x,
                                               unsigned short* __restrict__ xb) {
    int i = (blockIdx.x * 256 + threadIdx.x) * 4;
    float4 v = *(const float4*)(x + i);
    ushort4 o;
    o.x = f2bf(v.x); o.y = f2bf(v.y); o.z = f2bf(v.z); o.w = f2bf(v.w);
    *(ushort4*)(xb + i) = o;
}

__global__ void __launch_bounds__(256) k_cvt_w4(
    const float* __restrict__ Wq, const float* __restrict__ Wk,
    const float* __restrict__ Wv, const float* __restrict__ Wp,
    unsigned short* __restrict__ WTbase) {
    const int z = blockIdx.y;
    const float* W = (z == 0) ? Wq : (z == 1) ? Wk : (z == 2) ? Wv : Wp;
    int idx = blockIdx.x * 256 + threadIdx.x;
    int n = idx >> 9, k = idx & 511;
    WTbase[(size_t)z * 262144 + idx] = f2bf(W[k * 512 + n]);
}

// ---------------------------------------------------------------- QKV proj
// z=0: Q row-major [b*N][U]
// z=1: K8 layout [b][d>>3][key][d&7]
// z=2: V8 layout [b][key>>3][d][key&7]
__global__ void __launch_bounds__(256, 2) k_proj(
    const unsigned short* __restrict__ Xb,
    const unsigned short* __restrict__ WqT, const unsigned short* __restrict__ WkT,
    const unsigned short* __restrict__ WvT,
    const float* __restrict__ bq, const float* __restrict__ bk, const float* __restrict__ bv,
    unsigned short* __restrict__ Q, unsigned short* __restrict__ K8,
    unsigned short* __restrict__ V8)
{
    __shared__ __align__(16) unsigned short As[128 * 32];
    __shared__ __align__(16) unsigned short Bs[128 * 32];
    const int z = blockIdx.z;
    const unsigned short* WT = (z == 0) ? WqT : (z == 1) ? WkT : WvT;
    const float* bias = (z == 0) ? bq : (z == 1) ? bk : bv;
    const int t = threadIdx.x, wave = t >> 6, lane = t & 63;
    const int quad = lane >> 4, l16 = lane & 15;
    const int m0 = blockIdx.x * 128, n0 = blockIdx.y * 128;
    const int wm = wave >> 1, wn = wave & 1;

    const int srow = wave * 32 + (lane >> 2);
    const int scol = (lane & 3) * 8;
    const unsigned short* gA = Xb + (size_t)(m0 + srow) * UU + scol;
    const unsigned short* gB = WT + (size_t)(n0 + srow) * UU + scol;
    unsigned short* lA = As + wave * 1024;
    unsigned short* lB = Bs + wave * 1024;

    floatx4 acc[4][4] = {};

    for (int k0 = 0; k0 < UU; k0 += 32) {
        GLL16(gA + k0, lA);
        GLL16(gA + k0 + 16 * UU, lA + 512);
        GLL16(gB + k0, lB);
        GLL16(gB + k0 + 16 * UU, lB + 512);
        __syncthreads();
        short8 a[4], b[4];
        #pragma unroll
        for (int i = 0; i < 4; i++)
            a[i] = *(const short8*)(As + (wm * 64 + i * 16 + l16) * 32 + quad * 8);
        #pragma unroll
        for (int j = 0; j < 4; j++)
            b[j] = *(const short8*)(Bs + (wn * 64 + j * 16 + l16) * 32 + quad * 8);
        #pragma unroll
        for (int i = 0; i < 4; i++)
            #pragma unroll
            for (int j = 0; j < 4; j++)
                acc[i][j] = mfma16(a[i], b[j], acc[i][j]);
        __syncthreads();
    }

    #pragma unroll
    for (int j = 0; j < 4; j++) {
        const int n = n0 + wn * 64 + j * 16 + l16;
        const float bv_ = bias[n];
        #pragma unroll
        for (int i = 0; i < 4; i++) {
            const int mb = m0 + wm * 64 + i * 16 + quad * 4;
            const int bb = mb >> 12, tok = mb & (NN - 1);
            if (z == 0) {
                #pragma unroll
                for (int r = 0; r < 4; r++)
                    Q[(size_t)(mb + r) * UU + n] = f2bf(acc[i][j][r] + bv_);
            } else if (z == 1) {
                const size_t base = (size_t)bb * NN * UU + (size_t)(n >> 3) * (NN * 8)
                                  + (size_t)tok * 8 + (n & 7);
                #pragma unroll
                for (int r = 0; r < 4; r++)
                    K8[base + (size_t)r * 8] = f2bf(acc[i][j][r] + bv_);
            } else {
                ushort4 o;
                o.x = f2bf(acc[i][j][0] + bv_);
                o.y = f2bf(acc[i][j][1] + bv_);
                o.z = f2bf(acc[i][j][2] + bv_);
                o.w = f2bf(acc[i][j][3] + bv_);
                *(ushort4*)(V8 + (size_t)bb * NN * UU + (size_t)(tok >> 3) * (UU * 8)
                            + (size_t)n * 8 + (tok & 7)) = o;
            }
        }
    }
}

// ---------------------------------------------------------------- flash attention
// 8 waves = (rg 0..1, dh 0..3). BM=64 q-rows/block, BN=32 keys/iter, 128 iters.
// S: wave = 32x32 tile (rg) over dim-quarter dh (8 mfma32); partials merged
//    2-buffer write-then-RMW. PV: wave = 32 rows x 128 dims (dh) x 32 keys.
// Staging: V(kt+32) issued at iter top (drains at iter end), K(kt+32) issued
// after S-buffer-free barrier. Intra-iter barriers are lgkm-only (no vmcnt
// drain) so staging stays in flight.
__global__ void __launch_bounds__(512, 2) k_flash(
    const unsigned short* __restrict__ Q,
    const unsigned short* __restrict__ K8,
    const unsigned short* __restrict__ V8,
    unsigned short* __restrict__ ctx)
{
    __shared__ __align__(16) char smem[122624];
    unsigned short* Ks  = (unsigned short*)smem;              // 32 KB [dc64][key32][8]
    unsigned short* Vs0 = (unsigned short*)(smem + 32768);    // 32 KB [kc4][d512][8]
    unsigned short* Vs1 = (unsigned short*)(smem + 65536);    // 32 KB
    float*          Sb0 = (float*)(smem + 98304);             // 64 x 36 f32
    float*          Sb1 = (float*)(smem + 107520);            // 64 x 36 f32
    unsigned short* P_l = (unsigned short*)(smem + 116736);   // 64 x 40 bf16
    float*          m_l = (float*)(smem + 121856);
    float*          l_l = m_l + 64;
    float*          a_l = m_l + 128;

    const int b = blockIdx.y, q0 = blockIdx.x * 64;
    const int t = threadIdx.x, wave = t >> 6, lane = t & 63;
    const int l31 = lane & 31, ah = lane >> 5;
    const int rg = wave >> 2, dh = wave & 3;   // S: dim-quarter; PV: d-quarter

    if (t < 64) { m_l[t] = -INFINITY; l_l[t] = 0.f; }

    // Q frags: rows rg*32 + l31, dims dh*128 + ks*16 + ah*8 + j  (32 VGPR)
    const unsigned short* qp = Q + (size_t)(b * NN + q0 + rg * 32 + l31) * UU
                             + dh * 128 + ah * 8;
    short8 qf[8];
    #pragma unroll
    for (int ks = 0; ks < 8; ks++) qf[ks] = *(const short8*)(qp + ks * 16);

    const unsigned short* K8b = K8 + (size_t)b * NN * UU;
    const unsigned short* V8b = V8 + (size_t)b * NN * UU;

    // prologue: stage K(0) and V(0)->Vs0
    #pragma unroll
    for (int j = 0; j < 4; j++) {
        const int i = wave * 4 + j;
        GLL16(K8b + (size_t)(i * 2 + ah) * (NN * 8) + (size_t)l31 * 8,
              Ks + i * 512 + lane * 8);
        GLL16(V8b + (size_t)i * 512 + lane * 8, Vs0 + i * 512 + lane * 8);
    }

    floatx16 o[4] = {};
    const float sscale = 0.04419417382415922f * 1.4426950408889634f;  // scale*log2e
    int cur = 0;

    __syncthreads();  // one full drain: K(0)/V(0) staged, stats init visible

    for (int kt = 0; kt < NN; kt += 32) {
        unsigned short* Vc = cur ? Vs1 : Vs0;
        unsigned short* Vn = cur ? Vs0 : Vs1;

        // stage V(kt+32) -> Vn: in flight across the whole iteration
        if (kt + 32 < NN) {
            #pragma unroll
            for (int j = 0; j < 4; j++) {
                const int i = wave * 4 + j;
                GLL16(V8b + (size_t)(kt + 32) * 512 + (size_t)i * 512 + lane * 8,
                      Vn + i * 512 + lane * 8);
            }
        }

        // ---- S partial: 32 rows (rg) x 32 keys x 128 dims (dh)
        floatx16 sacc = {};
        #pragma unroll
        for (int ks = 0; ks < 8; ks++) {
            const int dc = dh * 16 + ks * 2 + ah;
            short8 bfrag = *(const short8*)(Ks + dc * 256 + l31 * 8);
            sacc = mfma32(qf[ks], bfrag, sacc);
        }
        float* Sb = (dh & 1) ? Sb1 : Sb0;
        if (dh < 2) {
            #pragma unroll
            for (int r = 0; r < 16; r++) {
                const int row = rg * 32 + (r & 3) + 8 * (r >> 2) + 4 * ah;
                Sb[row * 36 + l31] = sacc[r] * sscale;
            }
        }
        BAR_LGKM;   // b1: dh<2 partials visible
        if (dh >= 2) {
            #pragma unroll
            for (int r = 0; r < 16; r++) {
                const int row = rg * 32 + (r & 3) + 8 * (r >> 2) + 4 * ah;
                Sb[row * 36 + l31] += sacc[r] * sscale;
            }
        }
        BAR_LGKM;   // b2: S complete; Ks reads done

        // ---- online softmax (8 threads per row, 4 cols each)
        {
            const int row = t >> 3, c4 = (t & 7) * 4;
            float4 v0 = *(const float4*)(Sb0 + row * 36 + c4);
            float4 v1 = *(const float4*)(Sb1 + row * 36 + c4);
            float4 s;
            s.x = v0.x + v1.x; s.y = v0.y + v1.y;
            s.z = v0.z + v1.z; s.w = v0.w + v1.w;
            float mx = fmaxf(fmaxf(s.x, s.y), fmaxf(s.z, s.w));
            mx = fmaxf(mx, __shfl_xor(mx, 1, 8));
            mx = fmaxf(mx, __shfl_xor(mx, 2, 8));
            mx = fmaxf(mx, __shfl_xor(mx, 4, 8));
            const float m_old = m_l[row];
            const float m_new = fmaxf(m_old, mx);
            ushort4 pv;
            pv.x = f2bf(exp2f(s.x - m_new));
            pv.y = f2bf(exp2f(s.y - m_new));
            pv.z = f2bf(exp2f(s.z - m_new));
            pv.w = f2bf(exp2f(s.w - m_new));
            float sum = bf2f(pv.x) + bf2f(pv.y) + bf2f(pv.z) + bf2f(pv.w);
            *(ushort4*)(P_l + row * 40 + c4) = pv;
            sum += __shfl_xor(sum, 1, 8);
            sum += __shfl_xor(sum, 2, 8);
            sum += __shfl_xor(sum, 4, 8);
            if ((t & 7) == 0) {
                const float alpha = exp2f(m_old - m_new);
                a_l[row] = alpha;
                m_l[row] = m_new;
                l_l[row] = l_l[row] * alpha + sum;
            }
        }
        BAR_LGKM;   // b3: P/stats visible

        // stage K(kt+32) in place (Ks reads finished at b2); drains at iter end
        if (kt + 32 < NN) {
            #pragma unroll
            for (int j = 0; j < 4; j++) {
                const int i = wave * 4 + j;
                GLL16(K8b + (size_t)(i * 2 + ah) * (NN * 8) + (size_t)(kt + 32 + l31) * 8,
                      Ks + i * 512 + lane * 8);
            }
        }

        // ---- PV: O[32 rows (rg)][128 dims (dh)] += P @ V (32 keys)
        float alv[16];
        #pragma unroll
        for (int g = 0; g < 4; g++) {
            float4 v = *(const float4*)(a_l + rg * 32 + ah * 4 + g * 8);
            alv[g * 4 + 0] = v.x; alv[g * 4 + 1] = v.y;
            alv[g * 4 + 2] = v.z; alv[g * 4 + 3] = v.w;
        }
        bool ns = false;
        #pragma unroll
        for (int r = 0; r < 16; r++) ns |= (alv[r] != 1.0f);
        if (__any(ns)) {   // skip o-rescale when row maxes unchanged (common)
            #pragma unroll
            for (int dt = 0; dt < 4; dt++)
                #pragma unroll
                for (int r = 0; r < 16; r++)
                    o[dt][r] *= alv[r];
        }
        short8 pa[2];
        #pragma unroll
        for (int ks = 0; ks < 2; ks++)
            pa[ks] = *(const short8*)(P_l + (rg * 32 + l31) * 40 + ks * 16 + ah * 8);
        #pragma unroll
        for (int dt = 0; dt < 4; dt++) {
            #pragma unroll
            for (int ks = 0; ks < 2; ks++) {
                short8 vb = *(const short8*)(Vc + (ks * 2 + ah) * 4096
                                             + (dh * 128 + dt * 32 + l31) * 8);
                o[dt] = mfma32(pa[ks], vb, o[dt]);
            }
        }
        BAR_ALL;   // iter end: PV/P reads done; K(kt+32)/V(kt+32) staged
        cur ^= 1;
    }

    // ---- epilogue: normalize, store (each wave owns disjoint rows x dims)
    float lnv[16];
    #pragma unroll
    for (int g = 0; g < 4; g++) {
        float4 v = *(const float4*)(l_l + rg * 32 + ah * 4 + g * 8);
        lnv[g * 4 + 0] = 1.f / v.x; lnv[g * 4 + 1] = 1.f / v.y;
        lnv[g * 4 + 2] = 1.f / v.z; lnv[g * 4 + 3] = 1.f / v.w;
    }
    #pragma unroll
    for (int dt = 0; dt < 4; dt++) {
        #pragma unroll
        for (int r = 0; r < 16; r++) {
            const int row = q0 + rg * 32 + (r & 3) + 8 * (r >> 2) + 4 * ah;
            const int d = dh * 128 + dt * 32 + l31;
            ctx[(size_t)(b * NN + row) * UU + d] = f2bf(o[dt][r] * lnv[r]);
        }
    }
}

// ---------------------------------------------------------------- out proj + residual
__global__ void __launch_bounds__(256, 2) k_out(
    const unsigned short* __restrict__ Cx,
    const unsigned short* __restrict__ WpT,
    const float* __restrict__ bp,
    const float* __restrict__ x,
    float* __restrict__ out)
{
    __shared__ __align__(16) unsigned short As[128 * 32];
    __shared__ __align__(16) unsigned short Bs[128 * 32];
    const int t = threadIdx.x, wave = t >> 6, lane = t & 63;
    const int quad = lane >> 4, l16 = lane & 15;
    const int m0 = blockIdx.x * 128, n0 = blockIdx.y * 128;
    const int wm = wave >> 1, wn = wave & 1;
    const int srow = wave * 32 + (lane >> 2);
    const int scol = (lane & 3) * 8;
    const unsigned short* gA = Cx + (size_t)(m0 + srow) * UU + scol;
    const unsigned short* gB = WpT + (size_t)(n0 + srow) * UU + scol;
    unsigned short* lA = As + wave * 1024;
    unsigned short* lB = Bs + wave * 1024;

    floatx4 acc[4][4] = {};

    for (int k0 = 0; k0 < UU; k0 += 32) {
        GLL16(gA + k0, lA);
        GLL16(gA + k0 + 16 * UU, lA + 512);
        GLL16(gB + k0, lB);
        GLL16(gB + k0 + 16 * UU, lB + 512);
        __syncthreads();
        short8 a[4], b[4];
        #pragma unroll
        for (int i = 0; i < 4; i++)
            a[i] = *(const short8*)(As + (wm * 64 + i * 16 + l16) * 32 + quad * 8);
        #pragma unroll
        for (int j = 0; j < 4; j++)
            b[j] = *(const short8*)(Bs + (wn * 64 + j * 16 + l16) * 32 + quad * 8);
        #pragma unroll
        for (int i = 0; i < 4; i++)
            #pragma unroll
            for (int j = 0; j < 4; j++)
                acc[i][j] = mfma16(a[i], b[j], acc[i][j]);
        __syncthreads();
    }

    #pragma unroll
    for (int j = 0; j < 4; j++) {
        const int n = n0 + wn * 64 + j * 16 + l16;
        const float bv_ = bp[n];
        #pragma unroll
        for (int i = 0; i < 4; i++) {
            const int mb = m0 + wm * 64 + i * 16 + quad * 4;
            #pragma unroll
            for (int r = 0; r < 4; r++) {
                const size_t idx = (size_t)(mb + r) * UU + n;
                out[idx] = acc[i][j][r] + bv_ + x[idx];
            }
        }
    }
}

// ---------------------------------------------------------------- launch
extern "C" void kernel_launch(void* const* d_in, const int* in_sizes, int n_in,
                              void* d_out, int out_size, void* d_ws, size_t ws_size,
                              hipStream_t stream)
{
    const float* x  = (const float*)d_in[0];
    const float* Wq = (const float*)d_in[1];
    const float* bq = (const float*)d_in[2];
    const float* Wk = (const float*)d_in[3];
    const float* bk = (const float*)d_in[4];
    const float* Wv = (const float*)d_in[5];
    const float* bv = (const float*)d_in[6];
    const float* Wp = (const float*)d_in[7];
    const float* bp = (const float*)d_in[8];
    float* out = (float*)d_out;

    char* ws = (char*)d_ws;
    unsigned short* Xb  = (unsigned short*)(ws);              // 16 MB  bf16 x
    unsigned short* WTb = (unsigned short*)(ws + 16777216);   // 4 x 512 KB contiguous
    unsigned short* WqT = WTb;
    unsigned short* WkT = WTb + 262144;
    unsigned short* WvT = WTb + 524288;
    unsigned short* WpT = WTb + 786432;
    unsigned short* Qm  = (unsigned short*)(ws + 18874368);   // 16 MB [b*N][U]
    unsigned short* K8m = (unsigned short*)(ws + 35651584);   // 16 MB [b][d>>3][key][d&7]
    unsigned short* V8m = (unsigned short*)(ws + 52428800);   // 16 MB [b][key>>3][d][key&7]
    unsigned short* Cx  = (unsigned short*)(ws + 69206016);   // 16 MB [b*N][U]

    hipLaunchKernelGGL(k_cvt_x, dim3(8192), dim3(256), 0, stream, x, Xb);
    hipLaunchKernelGGL(k_cvt_w4, dim3(1024, 4), dim3(256), 0, stream, Wq, Wk, Wv, Wp, WTb);
    hipLaunchKernelGGL(k_proj, dim3(128, 4, 3), dim3(256), 0, stream,
                       Xb, WqT, WkT, WvT, bq, bk, bv, Qm, K8m, V8m);
    hipLaunchKernelGGL(k_flash, dim3(64, 4), dim3(512), 0, stream, Qm, K8m, V8m, Cx);
    hipLaunchKernelGGL(k_out, dim3(128, 4), dim3(256), 0, stream, Cx, WpT, bp, x, out);
}

// Round 6
// 455.814 us; speedup vs baseline: 1.0927x; 1.0927x over previous
//
#include <hip/hip_runtime.h>
#include <hip/hip_bf16.h>
#include <math.h>

#define NB 4
#define NN 4096
#define UU 512

using short8   = __attribute__((ext_vector_type(8))) short;
using bf16x8   = __attribute__((ext_vector_type(8))) __bf16;
using floatx4  = __attribute__((ext_vector_type(4))) float;
using floatx16 = __attribute__((ext_vector_type(16))) float;

__device__ __forceinline__ floatx4 mfma16(short8 a, short8 b, floatx4 c) {
    return __builtin_amdgcn_mfma_f32_16x16x32_bf16(
        __builtin_bit_cast(bf16x8, a), __builtin_bit_cast(bf16x8, b), c, 0, 0, 0);
}
__device__ __forceinline__ floatx16 mfma32(short8 a, short8 b, floatx16 c) {
    return __builtin_amdgcn_mfma_f32_32x32x16_bf16(
        __builtin_bit_cast(bf16x8, a), __builtin_bit_cast(bf16x8, b), c, 0, 0, 0);
}

__device__ __forceinline__ unsigned short f2bf(float f) {
    union { float f; unsigned u; } v; v.f = f;
    return (unsigned short)((v.u + 0x7fffu + ((v.u >> 16) & 1u)) >> 16);
}
__device__ __forceinline__ float bf2f(unsigned short s) {
    union { unsigned u; float f; } v; v.u = ((unsigned)s) << 16; return v.f;
}

#define GLL16(gp, lp) __builtin_amdgcn_global_load_lds( \
    (const __attribute__((address_space(1))) void*)(gp), \
    (__attribute__((address_space(3))) void*)(lp), 16, 0, 0)

// ---------------------------------------------------------------- converts
__global__ void __launch_bounds__(256) k_cvt_x(const float* __restrict__ x,
                                               unsigned short* __restrict__ xb) {
    int i = (blockIdx.x * 256 + threadIdx.x) * 4;
    float4 v = *(const float4*)(x + i);
    ushort4 o;
    o.x = f2bf(v.x); o.y = f2bf(v.y); o.z = f2bf(v.z); o.w = f2bf(v.w);
    *(ushort4*)(xb + i) = o;
}

__global__ void __launch_bounds__(256) k_cvt_w4(
    const float* __restrict__ Wq, const float* __restrict__ Wk,
    const float* __restrict__ Wv, const float* __restrict__ Wp,
    unsigned short* __restrict__ WTbase) {
    const int z = blockIdx.y;
    const float* W = (z == 0) ? Wq : (z == 1) ? Wk : (z == 2) ? Wv : Wp;
    int idx = blockIdx.x * 256 + threadIdx.x;
    int n = idx >> 9, k = idx & 511;
    WTbase[(size_t)z * 262144 + idx] = f2bf(W[k * 512 + n]);
}

// ---------------------------------------------------------------- QKV proj
// z=0: Q row-major [b*N][U]
// z=1: K8 layout [b][d>>3][key][d&7]
// z=2: V8 layout [b][key>>3][d][key&7]
__global__ void __launch_bounds__(256, 2) k_proj(
    const unsigned short* __restrict__ Xb,
    const unsigned short* __restrict__ WqT, const unsigned short* __restrict__ WkT,
    const unsigned short* __restrict__ WvT,
    const float* __restrict__ bq, const float* __restrict__ bk, const float* __restrict__ bv,
    unsigned short* __restrict__ Q, unsigned short* __restrict__ K8,
    unsigned short* __restrict__ V8)
{
    __shared__ __align__(16) unsigned short As[128 * 32];
    __shared__ __align__(16) unsigned short Bs[128 * 32];
    const int z = blockIdx.z;
    const unsigned short* WT = (z == 0) ? WqT : (z == 1) ? WkT : WvT;
    const float* bias = (z == 0) ? bq : (z == 1) ? bk : bv;
    const int t = threadIdx.x, wave = t >> 6, lane = t & 63;
    const int quad = lane >> 4, l16 = lane & 15;
    const int m0 = blockIdx.x * 128, n0 = blockIdx.y * 128;
    const int wm = wave >> 1, wn = wave & 1;

    const int srow = wave * 32 + (lane >> 2);
    const int scol = (lane & 3) * 8;
    const unsigned short* gA = Xb + (size_t)(m0 + srow) * UU + scol;
    const unsigned short* gB = WT + (size_t)(n0 + srow) * UU + scol;
    unsigned short* lA = As + wave * 1024;
    unsigned short* lB = Bs + wave * 1024;

    floatx4 acc[4][4] = {};

    for (int k0 = 0; k0 < UU; k0 += 32) {
        GLL16(gA + k0, lA);
        GLL16(gA + k0 + 16 * UU, lA + 512);
        GLL16(gB + k0, lB);
        GLL16(gB + k0 + 16 * UU, lB + 512);
        __syncthreads();
        short8 a[4], b[4];
        #pragma unroll
        for (int i = 0; i < 4; i++)
            a[i] = *(const short8*)(As + (wm * 64 + i * 16 + l16) * 32 + quad * 8);
        #pragma unroll
        for (int j = 0; j < 4; j++)
            b[j] = *(const short8*)(Bs + (wn * 64 + j * 16 + l16) * 32 + quad * 8);
        #pragma unroll
        for (int i = 0; i < 4; i++)
            #pragma unroll
            for (int j = 0; j < 4; j++)
                acc[i][j] = mfma16(a[i], b[j], acc[i][j]);
        __syncthreads();
    }

    #pragma unroll
    for (int j = 0; j < 4; j++) {
        const int n = n0 + wn * 64 + j * 16 + l16;
        const float bv_ = bias[n];
        #pragma unroll
        for (int i = 0; i < 4; i++) {
            const int mb = m0 + wm * 64 + i * 16 + quad * 4;
            const int bb = mb >> 12, tok = mb & (NN - 1);
            if (z == 0) {
                #pragma unroll
                for (int r = 0; r < 4; r++)
                    Q[(size_t)(mb + r) * UU + n] = f2bf(acc[i][j][r] + bv_);
            } else if (z == 1) {
                const size_t base = (size_t)bb * NN * UU + (size_t)(n >> 3) * (NN * 8)
                                  + (size_t)tok * 8 + (n & 7);
                #pragma unroll
                for (int r = 0; r < 4; r++)
                    K8[base + (size_t)r * 8] = f2bf(acc[i][j][r] + bv_);
            } else {
                ushort4 o;
                o.x = f2bf(acc[i][j][0] + bv_);
                o.y = f2bf(acc[i][j][1] + bv_);
                o.z = f2bf(acc[i][j][2] + bv_);
                o.w = f2bf(acc[i][j][3] + bv_);
                *(ushort4*)(V8 + (size_t)bb * NN * UU + (size_t)(tok >> 3) * (UU * 8)
                            + (size_t)n * 8 + (tok & 7)) = o;
            }
        }
    }
}

// ---------------------------------------------------------------- flash attention
// BM=32 q-rows/block, BN=32 keys/iter, 512 thr (8 waves), grid 512 -> 2 blk/CU.
// Wave w owns dim-slice [w*64, w*64+64) for S and d-slice [w*64,+64) for PV:
// disjoint slices -> K/V fragments read DIRECTLY from L2 (coalesced b128),
// no K/V LDS, no staging barriers. 2 barriers/iter. Cross-block overlap hides
// softmax/barrier bubbles.
__global__ void __launch_bounds__(512, 4) k_flash(
    const unsigned short* __restrict__ Q,
    const unsigned short* __restrict__ K8,
    const unsigned short* __restrict__ V8,
    unsigned short* __restrict__ ctx)
{
    __shared__ __align__(16) float Sb[8][32 * 33];          // 33.8 KB
    __shared__ __align__(16) unsigned short P_l[32 * 36];   // 2.3 KB
    __shared__ float m_l[32], l_l[32], a_l[32];

    const int b = blockIdx.y, q0 = blockIdx.x * 32;
    const int t = threadIdx.x, w = t >> 6, lane = t & 63;
    const int l31 = lane & 31, ah = lane >> 5;

    if (t < 32) { m_l[t] = -INFINITY; l_l[t] = 0.f; }

    // Q frags: rows q0+l31, dims w*64 + ks*16 + ah*8 + j   (16 VGPR)
    const unsigned short* qp = Q + (size_t)(b * NN + q0 + l31) * UU + w * 64 + ah * 8;
    short8 qf[4];
    #pragma unroll
    for (int ks = 0; ks < 4; ks++) qf[ks] = *(const short8*)(qp + ks * 16);

    const unsigned short* K8b = K8 + (size_t)b * NN * UU;
    const unsigned short* V8b = V8 + (size_t)b * NN * UU;
    const float sscale = 0.04419417382415922f * 1.4426950408889634f;  // 1/sqrt(512)*log2e

    // ---- peel: S(0)
    {
        floatx16 sacc = {};
        #pragma unroll
        for (int ks = 0; ks < 4; ks++) {
            short8 kf = *(const short8*)(K8b + (size_t)(w * 8 + ks * 2 + ah) * (NN * 8)
                                         + (size_t)l31 * 8);
            sacc = mfma32(qf[ks], kf, sacc);
        }
        #pragma unroll
        for (int r = 0; r < 16; r++)
            Sb[w][((r & 3) + 8 * (r >> 2) + 4 * ah) * 33 + l31] = sacc[r] * sscale;
    }
    __syncthreads();
    // ---- softmax(0)
    {
        const int row = t >> 4, c0 = (t & 15) * 2;
        float s0 = 0.f, s1 = 0.f;
        #pragma unroll
        for (int u = 0; u < 8; u++) {
            float2 v = *(const float2*)(&Sb[u][row * 33 + c0]);
            s0 += v.x; s1 += v.y;
        }
        float mx = fmaxf(s0, s1);
        mx = fmaxf(mx, __shfl_xor(mx, 1, 16));
        mx = fmaxf(mx, __shfl_xor(mx, 2, 16));
        mx = fmaxf(mx, __shfl_xor(mx, 4, 16));
        mx = fmaxf(mx, __shfl_xor(mx, 8, 16));
        const float m_old = m_l[row];
        const float m_new = fmaxf(m_old, mx);
        ushort2 pv;
        pv.x = f2bf(exp2f(s0 - m_new));
        pv.y = f2bf(exp2f(s1 - m_new));
        *(ushort2*)(P_l + row * 36 + c0) = pv;
        float sum = bf2f(pv.x) + bf2f(pv.y);
        sum += __shfl_xor(sum, 1, 16);
        sum += __shfl_xor(sum, 2, 16);
        sum += __shfl_xor(sum, 4, 16);
        sum += __shfl_xor(sum, 8, 16);
        if ((t & 15) == 0) {
            const float alpha = exp2f(m_old - m_new);
            a_l[row] = alpha;
            m_l[row] = m_new;
            l_l[row] = l_l[row] * alpha + sum;
        }
    }
    __syncthreads();

    floatx16 o[2] = {};

    for (int kt = 0; kt < NN; kt += 32) {
        // ---- PV(kt): O[32 rows][dims w*64..+63] += P @ V, 32 keys
        short8 vf[2][2];
        #pragma unroll
        for (int ks = 0; ks < 2; ks++)
            #pragma unroll
            for (int dt = 0; dt < 2; dt++)
                vf[ks][dt] = *(const short8*)(V8b + (size_t)((kt >> 3) + ks * 2 + ah) * (UU * 8)
                                              + (size_t)(w * 64 + dt * 32 + l31) * 8);
        float alv[16];
        #pragma unroll
        for (int g = 0; g < 4; g++) {
            float4 v = *(const float4*)(a_l + ah * 4 + g * 8);
            alv[g * 4 + 0] = v.x; alv[g * 4 + 1] = v.y;
            alv[g * 4 + 2] = v.z; alv[g * 4 + 3] = v.w;
        }
        bool ns = false;
        #pragma unroll
        for (int r = 0; r < 16; r++) ns |= (alv[r] != 1.0f);
        if (__any(ns)) {
            #pragma unroll
            for (int dt = 0; dt < 2; dt++)
                #pragma unroll
                for (int r = 0; r < 16; r++)
                    o[dt][r] *= alv[r];
        }
        short8 pa[2];
        #pragma unroll
        for (int ks = 0; ks < 2; ks++)
            pa[ks] = *(const short8*)(P_l + l31 * 36 + ks * 16 + ah * 8);
        #pragma unroll
        for (int dt = 0; dt < 2; dt++)
            #pragma unroll
            for (int ks = 0; ks < 2; ks++)
                o[dt] = mfma32(pa[ks], vf[ks][dt], o[dt]);

        if (kt + 32 < NN) {
            // ---- S(kt+32): same MFMA burst, then 2 barriers around softmax
            floatx16 sacc = {};
            #pragma unroll
            for (int ks = 0; ks < 4; ks++) {
                short8 kf = *(const short8*)(K8b + (size_t)(w * 8 + ks * 2 + ah) * (NN * 8)
                                             + (size_t)(kt + 32 + l31) * 8);
                sacc = mfma32(qf[ks], kf, sacc);
            }
            #pragma unroll
            for (int r = 0; r < 16; r++)
                Sb[w][((r & 3) + 8 * (r >> 2) + 4 * ah) * 33 + l31] = sacc[r] * sscale;
            __syncthreads();   // Sb complete; P_l reads (PV) done
            {
                const int row = t >> 4, c0 = (t & 15) * 2;
                float s0 = 0.f, s1 = 0.f;
                #pragma unroll
                for (int u = 0; u < 8; u++) {
                    float2 v = *(const float2*)(&Sb[u][row * 33 + c0]);
                    s0 += v.x; s1 += v.y;
                }
                float mx = fmaxf(s0, s1);
                mx = fmaxf(mx, __shfl_xor(mx, 1, 16));
                mx = fmaxf(mx, __shfl_xor(mx, 2, 16));
                mx = fmaxf(mx, __shfl_xor(mx, 4, 16));
                mx = fmaxf(mx, __shfl_xor(mx, 8, 16));
                const float m_old = m_l[row];
                const float m_new = fmaxf(m_old, mx);
                ushort2 pv;
                pv.x = f2bf(exp2f(s0 - m_new));
                pv.y = f2bf(exp2f(s1 - m_new));
                *(ushort2*)(P_l + row * 36 + c0) = pv;
                float sum = bf2f(pv.x) + bf2f(pv.y);
                sum += __shfl_xor(sum, 1, 16);
                sum += __shfl_xor(sum, 2, 16);
                sum += __shfl_xor(sum, 4, 16);
                sum += __shfl_xor(sum, 8, 16);
                if ((t & 15) == 0) {
                    const float alpha = exp2f(m_old - m_new);
                    a_l[row] = alpha;
                    m_l[row] = m_new;
                    l_l[row] = l_l[row] * alpha + sum;
                }
            }
            __syncthreads();   // P_l/stats visible for PV(kt+32)
        }
    }

    // ---- epilogue: normalize, store (each wave owns disjoint 64-d slice)
    float lnv[16];
    #pragma unroll
    for (int g = 0; g < 4; g++) {
        float4 v = *(const float4*)(l_l + ah * 4 + g * 8);
        lnv[g * 4 + 0] = 1.f / v.x; lnv[g * 4 + 1] = 1.f / v.y;
        lnv[g * 4 + 2] = 1.f / v.z; lnv[g * 4 + 3] = 1.f / v.w;
    }
    #pragma unroll
    for (int dt = 0; dt < 2; dt++) {
        #pragma unroll
        for (int r = 0; r < 16; r++) {
            const int row = q0 + (r & 3) + 8 * (r >> 2) + 4 * ah;
            const int d = w * 64 + dt * 32 + l31;
            ctx[(size_t)(b * NN + row) * UU + d] = f2bf(o[dt][r] * lnv[r]);
        }
    }
}

// ---------------------------------------------------------------- out proj + residual
__global__ void __launch_bounds__(256, 2) k_out(
    const unsigned short* __restrict__ Cx,
    const unsigned short* __restrict__ WpT,
    const float* __restrict__ bp,
    const float* __restrict__ x,
    float* __restrict__ out)
{
    __shared__ __align__(16) unsigned short As[128 * 32];
    __shared__ __align__(16) unsigned short Bs[128 * 32];
    const int t = threadIdx.x, wave = t >> 6, lane = t & 63;
    const int quad = lane >> 4, l16 = lane & 15;
    const int m0 = blockIdx.x * 128, n0 = blockIdx.y * 128;
    const int wm = wave >> 1, wn = wave & 1;
    const int srow = wave * 32 + (lane >> 2);
    const int scol = (lane & 3) * 8;
    const unsigned short* gA = Cx + (size_t)(m0 + srow) * UU + scol;
    const unsigned short* gB = WpT + (size_t)(n0 + srow) * UU + scol;
    unsigned short* lA = As + wave * 1024;
    unsigned short* lB = Bs + wave * 1024;

    floatx4 acc[4][4] = {};

    for (int k0 = 0; k0 < UU; k0 += 32) {
        GLL16(gA + k0, lA);
        GLL16(gA + k0 + 16 * UU, lA + 512);
        GLL16(gB + k0, lB);
        GLL16(gB + k0 + 16 * UU, lB + 512);
        __syncthreads();
        short8 a[4], b[4];
        #pragma unroll
        for (int i = 0; i < 4; i++)
            a[i] = *(const short8*)(As + (wm * 64 + i * 16 + l16) * 32 + quad * 8);
        #pragma unroll
        for (int j = 0; j < 4; j++)
            b[j] = *(const short8*)(Bs + (wn * 64 + j * 16 + l16) * 32 + quad * 8);
        #pragma unroll
        for (int i = 0; i < 4; i++)
            #pragma unroll
            for (int j = 0; j < 4; j++)
                acc[i][j] = mfma16(a[i], b[j], acc[i][j]);
        __syncthreads();
    }

    #pragma unroll
    for (int j = 0; j < 4; j++) {
        const int n = n0 + wn * 64 + j * 16 + l16;
        const float bv_ = bp[n];
        #pragma unroll
        for (int i = 0; i < 4; i++) {
            const int mb = m0 + wm * 64 + i * 16 + quad * 4;
            #pragma unroll
            for (int r = 0; r < 4; r++) {
                const size_t idx = (size_t)(mb + r) * UU + n;
                out[idx] = acc[i][j][r] + bv_ + x[idx];
            }
        }
    }
}

// ---------------------------------------------------------------- launch
extern "C" void kernel_launch(void* const* d_in, const int* in_sizes, int n_in,
                              void* d_out, int out_size, void* d_ws, size_t ws_size,
                              hipStream_t stream)
{
    const float* x  = (const float*)d_in[0];
    const float* Wq = (const float*)d_in[1];
    const float* bq = (const float*)d_in[2];
    const float* Wk = (const float*)d_in[3];
    const float* bk = (const float*)d_in[4];
    const float* Wv = (const float*)d_in[5];
    const float* bv = (const float*)d_in[6];
    const float* Wp = (const float*)d_in[7];
    const float* bp = (const float*)d_in[8];
    float* out = (float*)d_out;

    char* ws = (char*)d_ws;
    unsigned short* Xb  = (unsigned short*)(ws);              // 16 MB  bf16 x
    unsigned short* WTb = (unsigned short*)(ws + 16777216);   // 4 x 512 KB contiguous
    unsigned short* WqT = WTb;
    unsigned short* WkT = WTb + 262144;
    unsigned short* WvT = WTb + 524288;
    unsigned short* WpT = WTb + 786432;
    unsigned short* Qm  = (unsigned short*)(ws + 18874368);   // 16 MB [b*N][U]
    unsigned short* K8m = (unsigned short*)(ws + 35651584);   // 16 MB [b][d>>3][key][d&7]
    unsigned short* V8m = (unsigned short*)(ws + 52428800);   // 16 MB [b][key>>3][d][key&7]
    unsigned short* Cx  = (unsigned short*)(ws + 69206016);   // 16 MB [b*N][U]

    hipLaunchKernelGGL(k_cvt_x, dim3(8192), dim3(256), 0, stream, x, Xb);
    hipLaunchKernelGGL(k_cvt_w4, dim3(1024, 4), dim3(256), 0, stream, Wq, Wk, Wv, Wp, WTb);
    hipLaunchKernelGGL(k_proj, dim3(128, 4, 3), dim3(256), 0, stream,
                       Xb, WqT, WkT, WvT, bq, bk, bv, Qm, K8m, V8m);
    hipLaunchKernelGGL(k_flash, dim3(128, 4), dim3(512), 0, stream, Qm, K8m, V8m, Cx);
    hipLaunchKernelGGL(k_out, dim3(128, 4), dim3(256), 0, stream, Cx, WpT, bp, x, out);
}